// Round 3
// baseline (672.501 us; speedup 1.0000x reference)
//
#include <hip/hip_runtime.h>
#include <hip/hip_bf16.h>

#define N_NODES 50000
#define N_EDGES 250000
#define DIN_ 256
#define DOUT_ 256
#define OH_ 16
#define KF_ 288   // 256 (h) + 16 (degrees) + 16 zero-pad -> 9 K-steps of 32

typedef short short8 __attribute__((ext_vector_type(8)));
typedef float f32x4 __attribute__((ext_vector_type(4)));

__device__ __forceinline__ unsigned short f2bf(float f) {
    unsigned u = __builtin_bit_cast(unsigned, f);
    return (unsigned short)((u + 0x7fffu + ((u >> 16) & 1u)) >> 16);
}

__device__ __forceinline__ uint4 pack8(float f0, float f1, float f2, float f3,
                                       float f4, float f5, float f6, float f7) {
    uint4 u;
    u.x = (unsigned)f2bf(f0) | ((unsigned)f2bf(f1) << 16);
    u.y = (unsigned)f2bf(f2) | ((unsigned)f2bf(f3) << 16);
    u.z = (unsigned)f2bf(f4) | ((unsigned)f2bf(f5) << 16);
    u.w = (unsigned)f2bf(f6) | ((unsigned)f2bf(f7) << 16);
    return u;
}

__device__ __forceinline__ float fast_rcp(float x) {
#if __has_builtin(__builtin_amdgcn_rcpf)
    return __builtin_amdgcn_rcpf(x);
#else
    return 1.0f / x;
#endif
}

// async global -> LDS, 16 bytes per lane (dest = wave-uniform base + lane*16)
__device__ __forceinline__ void gl_lds16(const void* g, void* l) {
    __builtin_amdgcn_global_load_lds(
        (const __attribute__((address_space(1))) unsigned int*)g,
        (__attribute__((address_space(3))) unsigned int*)l, 16, 0, 0);
}

// ---------- sort pipeline: counting sort of edges by scatter target ----------
__global__ void hist_kernel(const int* __restrict__ sc0, const int* __restrict__ sc1,
                            int* __restrict__ hist) {
    int e = blockIdx.x * 256 + threadIdx.x;
    if (e < N_EDGES) {
        atomicAdd(&hist[sc0[e]], 1);
        atomicAdd(&hist[N_NODES + sc1[e]], 1);
    }
}

// exclusive scan over hist[2*N_NODES] -> offs (single block, 1024 threads)
__global__ __launch_bounds__(1024) void scan_kernel(const int* __restrict__ hist,
                                                    int* __restrict__ offs) {
    __shared__ int part[1024];
    const int TOT = 2 * N_NODES;
    int tid = threadIdx.x;
    const int per = (TOT + 1023) / 1024;
    int base = tid * per;
    int s = 0;
    for (int i = 0; i < per; ++i) {
        int idx = base + i;
        if (idx < TOT) s += hist[idx];
    }
    part[tid] = s;
    __syncthreads();
    for (int d = 1; d < 1024; d <<= 1) {
        int add = (tid >= d) ? part[tid - d] : 0;
        __syncthreads();
        part[tid] += add;
        __syncthreads();
    }
    int excl = (tid == 0) ? 0 : part[tid - 1];
    for (int i = 0; i < per; ++i) {
        int idx = base + i;
        if (idx < TOT) {
            offs[idx] = excl;
            excl += hist[idx];
        }
    }
}

// order[p] = edge id in sorted-by-target order; keys[p] = target node
__global__ void rank_kernel(const int* __restrict__ sc0, const int* __restrict__ sc1,
                            int* __restrict__ offs, int* __restrict__ order,
                            int* __restrict__ keys) {
    int e = blockIdx.x * 256 + threadIdx.x;
    if (e < N_EDGES) {
        int k0 = sc0[e];
        int p = atomicAdd(&offs[k0], 1);
        order[p] = e; keys[p] = k0;
        int k1 = sc1[e];
        int q = atomicAdd(&offs[N_NODES + k1], 1);
        order[q] = e; keys[q] = k1;
    }
}

// ---------- weight / input prep ----------
__global__ void prep_weights(const float* __restrict__ W_lin,
                             const float* __restrict__ W_k0,
                             const float* __restrict__ W_k1,
                             unsigned short* __restrict__ WT_lin,
                             unsigned short* __restrict__ WT_k0,
                             unsigned short* __restrict__ WT_k1) {
    int idx = blockIdx.x * 256 + threadIdx.x;
    if (idx < DOUT_ * DIN_) {
        int n = idx >> 8, k = idx & 255;
        WT_lin[idx] = f2bf(W_lin[k * DOUT_ + n]);
    }
    if (idx < DOUT_ * KF_) {
        int n = idx / KF_, k = idx - n * KF_;
        float v0 = 0.f, v1 = 0.f;
        if (k < DIN_ + OH_) {
            v0 = W_k0[k * DOUT_ + n];
            v1 = W_k1[k * DOUT_ + n];
        }
        WT_k0[idx] = f2bf(v0);
        WT_k1[idx] = f2bf(v1);
    }
}

__global__ void conv_h(const float* __restrict__ h, unsigned short* __restrict__ hbf) {
    int idx = blockIdx.x * 256 + threadIdx.x;
    const float4* s = (const float4*)(h + (size_t)idx * 8);
    float4 a = s[0], b = s[1];
    ((uint4*)hbf)[idx] = pack8(a.x, a.y, a.z, a.w, b.x, b.y, b.z, b.w);
}

// h3 = h @ W_lin + b_lin   (writes all of d_out)
__global__ __launch_bounds__(256) void main_gemm(const unsigned short* __restrict__ hbf,
                                                 const unsigned short* __restrict__ WT,
                                                 const float* __restrict__ bias,
                                                 float* __restrict__ out) {
    __shared__ unsigned short Alds[2][64][32];
    __shared__ unsigned short Blds[2][256][32];
    __shared__ float bias_lds[256];
    int tid = threadIdx.x;
    int w = tid >> 6, ln = tid & 63, l15 = ln & 15;
    int row0 = blockIdx.x * 64;
    bias_lds[tid] = bias[tid];

    int ar = row0 + w * 16 + (ln >> 2);
    if (ar >= N_NODES) ar = N_NODES - 1;
    int qs = (ln & 3) ^ ((ln >> 3) & 3);
    const unsigned short* asrc = hbf + (size_t)ar * DIN_ + qs * 8;
    int brow = w * 64;
    int swz = ((ln >> 4) ^ ((l15 >> 1) & 3)) * 8;

    f32x4 acc[16];
#pragma unroll
    for (int j = 0; j < 16; ++j) acc[j] = (f32x4)(0.f);

    gl_lds16(asrc, &Alds[0][w * 16][0]);
#pragma unroll
    for (int i = 0; i < 4; ++i) {
        int n = brow + i * 16 + (ln >> 2);
        gl_lds16(WT + (size_t)n * DIN_ + qs * 8, &Blds[0][brow + i * 16][0]);
    }
    __syncthreads();

    int buf = 0;
    for (int kk = 0; kk < 8; ++kk) {
        if (kk < 7) {
            gl_lds16(asrc + (kk + 1) * 32, &Alds[buf ^ 1][w * 16][0]);
#pragma unroll
            for (int i = 0; i < 4; ++i) {
                int n = brow + i * 16 + (ln >> 2);
                gl_lds16(WT + (size_t)n * DIN_ + (kk + 1) * 32 + qs * 8,
                         &Blds[buf ^ 1][brow + i * 16][0]);
            }
        }
        short8 af = *(const short8*)&Alds[buf][w * 16 + l15][swz];
#pragma unroll
        for (int j = 0; j < 16; ++j) {
            short8 bf = *(const short8*)&Blds[buf][j * 16 + l15][swz];
            acc[j] = __builtin_amdgcn_mfma_f32_16x16x32_bf16(af, bf, acc[j], 0, 0, 0);
        }
        __syncthreads();
        buf ^= 1;
    }

    int rbase = row0 + w * 16 + ((ln >> 4) << 2);
#pragma unroll
    for (int j = 0; j < 16; ++j) {
        int n = j * 16 + l15;
        float bv = bias_lds[n];
#pragma unroll
        for (int i = 0; i < 4; ++i) {
            int rr = rbase + i;
            if (rr < N_NODES) out[(size_t)rr * DOUT_ + n] = acc[j][i] + bv;
        }
    }
}

// One key term, edges processed in sorted-by-target order.
// out[key] += (1+eps) / ((1+exp(-(A0@W+b))) * (1+exp(-(A1@W+b)))), segment-summed.
__global__ __launch_bounds__(256) void edge_gemm(const unsigned short* __restrict__ hbf,
                                                 const int* __restrict__ pairs,     // [2][E]
                                                 const float* __restrict__ degrees, // [2][E][16]
                                                 const int* __restrict__ order_k,   // [E] sorted->edge
                                                 const int* __restrict__ keys_k,    // [E] sorted targets
                                                 const unsigned short* __restrict__ WT, // [256][288]
                                                 const float* __restrict__ bias,
                                                 const float* __restrict__ eps,
                                                 float* __restrict__ out) {
    __shared__ unsigned short Alds[2][2][64][32];   // 16 KB
    __shared__ unsigned short Blds[2][256][32];     // 32 KB (reused as reduction buf)
    __shared__ float bias_lds[256];
    __shared__ int tgt[64];
    int tid = threadIdx.x;
    int w = tid >> 6, ln = tid & 63, l15 = ln & 15;
    int e0 = blockIdx.x * 64;
    bias_lds[tid] = bias[tid];
    if (tid < 64) {
        int s = e0 + tid;
        tgt[tid] = (s < N_EDGES) ? keys_k[s] : -1;
    }

    int sA = e0 + w * 16 + (ln >> 2);
    if (sA >= N_EDGES) sA = N_EDGES - 1;
    int eA = order_k[sA];
    int p0 = pairs[eA];
    int p1 = pairs[N_EDGES + eA];
    int qs = (ln & 3) ^ ((ln >> 3) & 3);
    const unsigned short* a0src = hbf + (size_t)p0 * DIN_ + qs * 8;
    const unsigned short* a1src = hbf + (size_t)p1 * DIN_ + qs * 8;
    int brow = w * 64;
    int swz = ((ln >> 4) ^ ((l15 >> 1) & 3)) * 8;

    // register-path staging of kk=8 (degrees + zero pad), swizzled ds_write
    int r8 = tid >> 2, q8 = tid & 3;
    int m8 = (q8 ^ ((r8 >> 1) & 3)) * 8;
    int s8 = e0 + r8;
    if (s8 >= N_EDGES) s8 = N_EDGES - 1;
    int e8 = order_k[s8];

    f32x4 acc0[16], acc1[16];
#pragma unroll
    for (int j = 0; j < 16; ++j) { acc0[j] = (f32x4)(0.f); acc1[j] = (f32x4)(0.f); }

    gl_lds16(a0src, &Alds[0][0][w * 16][0]);
    gl_lds16(a1src, &Alds[0][1][w * 16][0]);
#pragma unroll
    for (int i = 0; i < 4; ++i) {
        int n = brow + i * 16 + (ln >> 2);
        gl_lds16(WT + (size_t)n * KF_ + qs * 8, &Blds[0][brow + i * 16][0]);
    }
    __syncthreads();

    int buf = 0;
    for (int kk = 0; kk < 9; ++kk) {
        if (kk < 8) {
#pragma unroll
            for (int i = 0; i < 4; ++i) {
                int n = brow + i * 16 + (ln >> 2);
                gl_lds16(WT + (size_t)n * KF_ + (kk + 1) * 32 + qs * 8,
                         &Blds[buf ^ 1][brow + i * 16][0]);
            }
            if (kk < 7) {
                gl_lds16(a0src + (kk + 1) * 32, &Alds[buf ^ 1][0][w * 16][0]);
                gl_lds16(a1src + (kk + 1) * 32, &Alds[buf ^ 1][1][w * 16][0]);
            } else {
#pragma unroll
                for (int t = 0; t < 2; ++t) {
                    uint4 v = make_uint4(0u, 0u, 0u, 0u);
                    if (q8 < 2) {
                        const float4* s4 = (const float4*)(degrees +
                            ((size_t)t * N_EDGES + e8) * OH_ + q8 * 8);
                        float4 a = s4[0], b = s4[1];
                        v = pack8(a.x, a.y, a.z, a.w, b.x, b.y, b.z, b.w);
                    }
                    *(uint4*)&Alds[buf ^ 1][t][r8][m8] = v;
                }
            }
        }
        short8 a0f = *(const short8*)&Alds[buf][0][w * 16 + l15][swz];
        short8 a1f = *(const short8*)&Alds[buf][1][w * 16 + l15][swz];
#pragma unroll
        for (int j = 0; j < 16; ++j) {
            short8 bf = *(const short8*)&Blds[buf][j * 16 + l15][swz];
            acc0[j] = __builtin_amdgcn_mfma_f32_16x16x32_bf16(a0f, bf, acc0[j], 0, 0, 0);
            acc1[j] = __builtin_amdgcn_mfma_f32_16x16x32_bf16(a1f, bf, acc1[j], 0, 0, 0);
        }
        __syncthreads();
        buf ^= 1;
    }

    // ---- epilogue: sigmoid product -> LDS chunk -> segmented reduce ----
    // reduction buffer aliases Blds (done with it after final barrier): [64][68] f32
    float* red = (float*)&Blds[0][0][0];
    float epv = 1.0f + eps[0];
    int rloc = w * 16 + ((ln >> 4) << 2);
    int c = tid & 63, Rb = (tid >> 6) * 16;

#pragma unroll
    for (int jc = 0; jc < 4; ++jc) {
#pragma unroll
        for (int jj = 0; jj < 4; ++jj) {
            float bv = bias_lds[(jc * 4 + jj) * 16 + l15];
#pragma unroll
            for (int i = 0; i < 4; ++i) {
                int row = rloc + i;
                float v = 0.f;
                if (e0 + row < N_EDGES) {
                    float a = acc0[jc * 4 + jj][i] + bv;
                    float b = acc1[jc * 4 + jj][i] + bv;
                    float ea = __expf(-a), eb = __expf(-b);
                    v = epv * fast_rcp((1.f + ea) * (1.f + eb));  // NaN-safe
                }
                red[row * 68 + jj * 16 + l15] = v;
            }
        }
        __syncthreads();
        // this thread reduces rows [Rb, Rb+16) of column c (output col jc*64+c)
        int n = jc * 64 + c;
        int runkey = tgt[Rb];
        float runsum = red[Rb * 68 + c];
        bool openL = true;  // first run may extend into previous range/block
        for (int r = Rb + 1; r < Rb + 16; ++r) {
            int k = tgt[r];
            float val = red[r * 68 + c];
            if (k != runkey) {
                if (runkey >= 0) {
                    float* dst = &out[(size_t)runkey * DOUT_ + n];
                    if (openL) atomicAdd(dst, runsum);
                    else *dst += runsum;   // interior run: globally exclusive
                }
                runkey = k;
                runsum = val;
                openL = false;
            } else {
                runsum += val;
            }
        }
        if (runkey >= 0) atomicAdd(&out[(size_t)runkey * DOUT_ + n], runsum); // open end
        __syncthreads();  // before next chunk overwrites red
    }
}

extern "C" void kernel_launch(void* const* d_in, const int* in_sizes, int n_in,
                              void* d_out, int out_size, void* d_ws, size_t ws_size,
                              hipStream_t stream) {
    const float* h        = (const float*)d_in[0];
    const int*   pairs_k0 = (const int*)d_in[1];
    const int*   pairs_k1 = (const int*)d_in[2];
    const float* deg_k0   = (const float*)d_in[3];
    const float* deg_k1   = (const float*)d_in[4];
    const int*   sc_k0    = (const int*)d_in[5];
    const int*   sc_k1    = (const int*)d_in[6];
    const float* W_lin    = (const float*)d_in[7];
    const float* b_lin    = (const float*)d_in[8];
    const float* W_k0     = (const float*)d_in[9];
    const float* b_k0     = (const float*)d_in[10];
    const float* W_k1     = (const float*)d_in[11];
    const float* b_k1     = (const float*)d_in[12];
    const float* eps_k0   = (const float*)d_in[13];
    const float* eps_k1   = (const float*)d_in[14];
    float* out = (float*)d_out;

    size_t ush_elems = (size_t)DOUT_ * DIN_ + 2 * (size_t)DOUT_ * KF_ + (size_t)N_NODES * DIN_;
    size_t int_elems = 2 * (size_t)N_NODES * 2 + 2 * (size_t)N_EDGES * 2;
    size_t need = ush_elems * sizeof(unsigned short) + int_elems * sizeof(int);
    if (ws_size < need) return;  // fail loudly in validation

    unsigned short* WT_lin = (unsigned short*)d_ws;
    unsigned short* WT_k0  = WT_lin + DOUT_ * DIN_;
    unsigned short* WT_k1  = WT_k0 + DOUT_ * KF_;
    unsigned short* h_bf   = WT_k1 + DOUT_ * KF_;
    int* hist  = (int*)(h_bf + (size_t)N_NODES * DIN_);
    int* offs  = hist + 2 * N_NODES;
    int* order = offs + 2 * N_NODES;     // [2*E]: k0 sorted then k1 sorted
    int* keys  = order + 2 * N_EDGES;    // [2*E]

    hipMemsetAsync(hist, 0, 2 * N_NODES * sizeof(int), stream);
    hist_kernel<<<(N_EDGES + 255) / 256, 256, 0, stream>>>(sc_k0, sc_k1, hist);
    scan_kernel<<<1, 1024, 0, stream>>>(hist, offs);
    rank_kernel<<<(N_EDGES + 255) / 256, 256, 0, stream>>>(sc_k0, sc_k1, offs, order, keys);

    prep_weights<<<(DOUT_ * KF_ + 255) / 256, 256, 0, stream>>>(W_lin, W_k0, W_k1,
                                                                WT_lin, WT_k0, WT_k1);
    conv_h<<<(N_NODES * DIN_ / 8) / 256, 256, 0, stream>>>(h, h_bf);
    main_gemm<<<(N_NODES + 63) / 64, 256, 0, stream>>>(h_bf, WT_lin, b_lin, out);
    edge_gemm<<<(N_EDGES + 63) / 64, 256, 0, stream>>>(h_bf, pairs_k0, deg_k0,
                                                       order, keys, WT_k0, b_k0, eps_k0, out);
    edge_gemm<<<(N_EDGES + 63) / 64, 256, 0, stream>>>(h_bf, pairs_k1, deg_k1,
                                                       order + N_EDGES, keys + N_EDGES,
                                                       WT_k1, b_k1, eps_k1, out);
}

// Round 4
// 426.155 us; speedup vs baseline: 1.5781x; 1.5781x over previous
//
#include <hip/hip_runtime.h>
#include <hip/hip_bf16.h>

#define N_NODES 50000
#define N_EDGES 250000
#define DIN_ 256
#define DOUT_ 256
#define OH_ 16
#define KF_ 288   // 256 (h) + 16 (degrees) + 16 zero-pad -> 9 K-steps of 32
#define NBLK_EDGE ((N_EDGES + 63) / 64)     // 3907
#define SCAN_TOT (2 * N_NODES)              // 100000
#define SCAN_NB ((SCAN_TOT + 255) / 256)    // 391

typedef short short8 __attribute__((ext_vector_type(8)));
typedef float f32x4 __attribute__((ext_vector_type(4)));

__device__ __forceinline__ unsigned short f2bf(float f) {
    unsigned u = __builtin_bit_cast(unsigned, f);
    return (unsigned short)((u + 0x7fffu + ((u >> 16) & 1u)) >> 16);
}

__device__ __forceinline__ uint4 pack8(float f0, float f1, float f2, float f3,
                                       float f4, float f5, float f6, float f7) {
    uint4 u;
    u.x = (unsigned)f2bf(f0) | ((unsigned)f2bf(f1) << 16);
    u.y = (unsigned)f2bf(f2) | ((unsigned)f2bf(f3) << 16);
    u.z = (unsigned)f2bf(f4) | ((unsigned)f2bf(f5) << 16);
    u.w = (unsigned)f2bf(f6) | ((unsigned)f2bf(f7) << 16);
    return u;
}

__device__ __forceinline__ float fast_rcp(float x) {
#if __has_builtin(__builtin_amdgcn_rcpf)
    return __builtin_amdgcn_rcpf(x);
#else
    return 1.0f / x;
#endif
}

// async global -> LDS, 16 bytes per lane (dest = wave-uniform base + lane*16)
__device__ __forceinline__ void gl_lds16(const void* g, void* l) {
    __builtin_amdgcn_global_load_lds(
        (const __attribute__((address_space(1))) unsigned int*)g,
        (__attribute__((address_space(3))) unsigned int*)l, 16, 0, 0);
}

// ---------- sort pipeline: counting sort of edges by scatter target ----------
__global__ void hist_kernel(const int* __restrict__ sc0, const int* __restrict__ sc1,
                            int* __restrict__ hist) {
    int e = blockIdx.x * 256 + threadIdx.x;
    if (e < N_EDGES) {
        atomicAdd(&hist[sc0[e]], 1);
        atomicAdd(&hist[N_NODES + sc1[e]], 1);
    }
}

__global__ void scan_pass1(const int* __restrict__ hist, int* __restrict__ partials) {
    __shared__ int sdata[256];
    int gid = blockIdx.x * 256 + threadIdx.x;
    sdata[threadIdx.x] = (gid < SCAN_TOT) ? hist[gid] : 0;
    __syncthreads();
    for (int d = 128; d > 0; d >>= 1) {
        if (threadIdx.x < d) sdata[threadIdx.x] += sdata[threadIdx.x + d];
        __syncthreads();
    }
    if (threadIdx.x == 0) partials[blockIdx.x] = sdata[0];
}

__global__ __launch_bounds__(512) void scan_pass2(int* __restrict__ partials) {
    __shared__ int s[512];
    int t = threadIdx.x;
    s[t] = (t < SCAN_NB) ? partials[t] : 0;
    __syncthreads();
    for (int d = 1; d < 512; d <<= 1) {
        int add = (t >= d) ? s[t - d] : 0;
        __syncthreads();
        s[t] += add;
        __syncthreads();
    }
    if (t < SCAN_NB) partials[t] = (t == 0) ? 0 : s[t - 1];   // exclusive
}

__global__ void scan_pass3(const int* __restrict__ hist, const int* __restrict__ partials,
                           int* __restrict__ offs) {
    __shared__ int s[256];
    int gid = blockIdx.x * 256 + threadIdx.x;
    int t = threadIdx.x;
    int v = (gid < SCAN_TOT) ? hist[gid] : 0;
    s[t] = v;
    __syncthreads();
    for (int d = 1; d < 256; d <<= 1) {
        int add = (t >= d) ? s[t - d] : 0;
        __syncthreads();
        s[t] += add;
        __syncthreads();
    }
    if (gid < SCAN_TOT) offs[gid] = partials[blockIdx.x] + s[t] - v;  // exclusive
}

// order[p] = edge id in sorted-by-target order; keys[p] = target node
__global__ void rank_kernel(const int* __restrict__ sc0, const int* __restrict__ sc1,
                            int* __restrict__ offs, int* __restrict__ order,
                            int* __restrict__ keys) {
    int e = blockIdx.x * 256 + threadIdx.x;
    if (e < N_EDGES) {
        int k0 = sc0[e];
        int p = atomicAdd(&offs[k0], 1);
        order[p] = e; keys[p] = k0;
        int k1 = sc1[e];
        int q = atomicAdd(&offs[N_NODES + k1], 1);
        order[q] = e; keys[q] = k1;
    }
}

// ---------- weight / input prep ----------
__global__ void prep_weights(const float* __restrict__ W_lin,
                             const float* __restrict__ W_k0,
                             const float* __restrict__ W_k1,
                             unsigned short* __restrict__ WT_lin,
                             unsigned short* __restrict__ WT_k0,
                             unsigned short* __restrict__ WT_k1) {
    int idx = blockIdx.x * 256 + threadIdx.x;
    if (idx < DOUT_ * DIN_) {
        int n = idx >> 8, k = idx & 255;
        WT_lin[idx] = f2bf(W_lin[k * DOUT_ + n]);
    }
    if (idx < DOUT_ * KF_) {
        int n = idx / KF_, k = idx - n * KF_;
        float v0 = 0.f, v1 = 0.f;
        if (k < DIN_ + OH_) {
            v0 = W_k0[k * DOUT_ + n];
            v1 = W_k1[k * DOUT_ + n];
        }
        WT_k0[idx] = f2bf(v0);
        WT_k1[idx] = f2bf(v1);
    }
}

__global__ void conv_h(const float* __restrict__ h, unsigned short* __restrict__ hbf) {
    int idx = blockIdx.x * 256 + threadIdx.x;
    const float4* s = (const float4*)(h + (size_t)idx * 8);
    float4 a = s[0], b = s[1];
    ((uint4*)hbf)[idx] = pack8(a.x, a.y, a.z, a.w, b.x, b.y, b.z, b.w);
}

// h3 = h @ W_lin + b_lin   (writes all of d_out)
__global__ __launch_bounds__(256) void main_gemm(const unsigned short* __restrict__ hbf,
                                                 const unsigned short* __restrict__ WT,
                                                 const float* __restrict__ bias,
                                                 float* __restrict__ out) {
    __shared__ unsigned short Alds[2][64][32];
    __shared__ unsigned short Blds[2][256][32];
    __shared__ float bias_lds[256];
    int tid = threadIdx.x;
    int w = tid >> 6, ln = tid & 63, l15 = ln & 15;
    int row0 = blockIdx.x * 64;
    bias_lds[tid] = bias[tid];

    int ar = row0 + w * 16 + (ln >> 2);
    if (ar >= N_NODES) ar = N_NODES - 1;
    int qs = (ln & 3) ^ ((ln >> 3) & 3);
    const unsigned short* asrc = hbf + (size_t)ar * DIN_ + qs * 8;
    int brow = w * 64;
    int swz = ((ln >> 4) ^ ((l15 >> 1) & 3)) * 8;

    f32x4 acc[16];
#pragma unroll
    for (int j = 0; j < 16; ++j) acc[j] = (f32x4)(0.f);

    gl_lds16(asrc, &Alds[0][w * 16][0]);
#pragma unroll
    for (int i = 0; i < 4; ++i) {
        int n = brow + i * 16 + (ln >> 2);
        gl_lds16(WT + (size_t)n * DIN_ + qs * 8, &Blds[0][brow + i * 16][0]);
    }
    __syncthreads();

    int buf = 0;
    for (int kk = 0; kk < 8; ++kk) {
        if (kk < 7) {
            gl_lds16(asrc + (kk + 1) * 32, &Alds[buf ^ 1][w * 16][0]);
#pragma unroll
            for (int i = 0; i < 4; ++i) {
                int n = brow + i * 16 + (ln >> 2);
                gl_lds16(WT + (size_t)n * DIN_ + (kk + 1) * 32 + qs * 8,
                         &Blds[buf ^ 1][brow + i * 16][0]);
            }
        }
        short8 af = *(const short8*)&Alds[buf][w * 16 + l15][swz];
#pragma unroll
        for (int j = 0; j < 16; ++j) {
            short8 bf = *(const short8*)&Blds[buf][j * 16 + l15][swz];
            acc[j] = __builtin_amdgcn_mfma_f32_16x16x32_bf16(af, bf, acc[j], 0, 0, 0);
        }
        __syncthreads();
        buf ^= 1;
    }

    int rbase = row0 + w * 16 + ((ln >> 4) << 2);
#pragma unroll
    for (int j = 0; j < 16; ++j) {
        int n = j * 16 + l15;
        float bv = bias_lds[n];
#pragma unroll
        for (int i = 0; i < 4; ++i) {
            int rr = rbase + i;
            if (rr < N_NODES) out[(size_t)rr * DOUT_ + n] = acc[j][i] + bv;
        }
    }
}

// Both key terms in one launch; blockIdx.x selects key. Edges in sorted-by-target order.
__global__ __launch_bounds__(256) void edge_gemm(const unsigned short* __restrict__ hbf,
                                                 const int* __restrict__ pairs0,
                                                 const int* __restrict__ pairs1,
                                                 const float* __restrict__ deg0,
                                                 const float* __restrict__ deg1,
                                                 const int* __restrict__ order_all, // [2E]
                                                 const int* __restrict__ keys_all,  // [2E]
                                                 const unsigned short* __restrict__ WT0,
                                                 const unsigned short* __restrict__ WT1,
                                                 const float* __restrict__ bias0,
                                                 const float* __restrict__ bias1,
                                                 const float* __restrict__ eps0,
                                                 const float* __restrict__ eps1,
                                                 float* __restrict__ out) {
    __shared__ unsigned short Alds[2][2][64][32];   // 16 KB
    __shared__ unsigned short Blds[2][256][32];     // 32 KB (reused as reduction buf)
    __shared__ float bias_lds[256];
    __shared__ int tgt[64];
    int kb = (blockIdx.x >= NBLK_EDGE) ? 1 : 0;
    int bx = blockIdx.x - kb * NBLK_EDGE;
    const int* pairs = kb ? pairs1 : pairs0;
    const float* degrees = kb ? deg1 : deg0;
    const int* order_k = order_all + kb * N_EDGES;
    const int* keys_k  = keys_all + kb * N_EDGES;
    const unsigned short* WT = kb ? WT1 : WT0;
    const float* bias = kb ? bias1 : bias0;
    const float* eps  = kb ? eps1 : eps0;

    int tid = threadIdx.x;
    int w = tid >> 6, ln = tid & 63, l15 = ln & 15;
    int e0 = bx * 64;
    bias_lds[tid] = bias[tid];
    if (tid < 64) {
        int s = e0 + tid;
        tgt[tid] = (s < N_EDGES) ? keys_k[s] : -1;
    }

    int sA = e0 + w * 16 + (ln >> 2);
    if (sA >= N_EDGES) sA = N_EDGES - 1;
    int eA = order_k[sA];
    int p0 = pairs[eA];
    int p1 = pairs[N_EDGES + eA];
    int qs = (ln & 3) ^ ((ln >> 3) & 3);
    const unsigned short* a0src = hbf + (size_t)p0 * DIN_ + qs * 8;
    const unsigned short* a1src = hbf + (size_t)p1 * DIN_ + qs * 8;
    int brow = w * 64;
    int swz = ((ln >> 4) ^ ((l15 >> 1) & 3)) * 8;

    int r8 = tid >> 2, q8 = tid & 3;
    int m8 = (q8 ^ ((r8 >> 1) & 3)) * 8;
    int s8 = e0 + r8;
    if (s8 >= N_EDGES) s8 = N_EDGES - 1;
    int e8 = order_k[s8];

    f32x4 acc0[16], acc1[16];
#pragma unroll
    for (int j = 0; j < 16; ++j) { acc0[j] = (f32x4)(0.f); acc1[j] = (f32x4)(0.f); }

    gl_lds16(a0src, &Alds[0][0][w * 16][0]);
    gl_lds16(a1src, &Alds[0][1][w * 16][0]);
#pragma unroll
    for (int i = 0; i < 4; ++i) {
        int n = brow + i * 16 + (ln >> 2);
        gl_lds16(WT + (size_t)n * KF_ + qs * 8, &Blds[0][brow + i * 16][0]);
    }
    __syncthreads();

    int buf = 0;
    for (int kk = 0; kk < 9; ++kk) {
        if (kk < 8) {
#pragma unroll
            for (int i = 0; i < 4; ++i) {
                int n = brow + i * 16 + (ln >> 2);
                gl_lds16(WT + (size_t)n * KF_ + (kk + 1) * 32 + qs * 8,
                         &Blds[buf ^ 1][brow + i * 16][0]);
            }
            if (kk < 7) {
                gl_lds16(a0src + (kk + 1) * 32, &Alds[buf ^ 1][0][w * 16][0]);
                gl_lds16(a1src + (kk + 1) * 32, &Alds[buf ^ 1][1][w * 16][0]);
            } else {
#pragma unroll
                for (int t = 0; t < 2; ++t) {
                    uint4 v = make_uint4(0u, 0u, 0u, 0u);
                    if (q8 < 2) {
                        const float4* s4 = (const float4*)(degrees +
                            ((size_t)t * N_EDGES + e8) * OH_ + q8 * 8);
                        float4 a = s4[0], b = s4[1];
                        v = pack8(a.x, a.y, a.z, a.w, b.x, b.y, b.z, b.w);
                    }
                    *(uint4*)&Alds[buf ^ 1][t][r8][m8] = v;
                }
            }
        }
        short8 a0f = *(const short8*)&Alds[buf][0][w * 16 + l15][swz];
        short8 a1f = *(const short8*)&Alds[buf][1][w * 16 + l15][swz];
#pragma unroll
        for (int j = 0; j < 16; ++j) {
            short8 bf = *(const short8*)&Blds[buf][j * 16 + l15][swz];
            acc0[j] = __builtin_amdgcn_mfma_f32_16x16x32_bf16(a0f, bf, acc0[j], 0, 0, 0);
            acc1[j] = __builtin_amdgcn_mfma_f32_16x16x32_bf16(a1f, bf, acc1[j], 0, 0, 0);
        }
        __syncthreads();
        buf ^= 1;
    }

    // ---- epilogue: sigmoid product -> LDS chunk -> segmented reduce (all-atomic flush) ----
    float* red = (float*)&Blds[0][0][0];   // [64][68]
    float epv = 1.0f + eps[0];
    int rloc = w * 16 + ((ln >> 4) << 2);
    int c = tid & 63, Rb = (tid >> 6) * 16;

#pragma unroll
    for (int jc = 0; jc < 4; ++jc) {
#pragma unroll
        for (int jj = 0; jj < 4; ++jj) {
            float bv = bias_lds[(jc * 4 + jj) * 16 + l15];
#pragma unroll
            for (int i = 0; i < 4; ++i) {
                int row = rloc + i;
                float v = 0.f;
                if (e0 + row < N_EDGES) {
                    float a = acc0[jc * 4 + jj][i] + bv;
                    float b = acc1[jc * 4 + jj][i] + bv;
                    float ea = __expf(-a), eb = __expf(-b);
                    v = epv * fast_rcp((1.f + ea) * (1.f + eb));
                }
                red[row * 68 + jj * 16 + l15] = v;
            }
        }
        __syncthreads();
        int n = jc * 64 + c;
        int runkey = tgt[Rb];
        float runsum = red[Rb * 68 + c];
        for (int r = Rb + 1; r < Rb + 16; ++r) {
            int k = tgt[r];
            float val = red[r * 68 + c];
            if (k != runkey) {
                if (runkey >= 0) atomicAdd(&out[(size_t)runkey * DOUT_ + n], runsum);
                runkey = k;
                runsum = val;
            } else {
                runsum += val;
            }
        }
        if (runkey >= 0) atomicAdd(&out[(size_t)runkey * DOUT_ + n], runsum);
        __syncthreads();
    }
}

extern "C" void kernel_launch(void* const* d_in, const int* in_sizes, int n_in,
                              void* d_out, int out_size, void* d_ws, size_t ws_size,
                              hipStream_t stream) {
    const float* h        = (const float*)d_in[0];
    const int*   pairs_k0 = (const int*)d_in[1];
    const int*   pairs_k1 = (const int*)d_in[2];
    const float* deg_k0   = (const float*)d_in[3];
    const float* deg_k1   = (const float*)d_in[4];
    const int*   sc_k0    = (const int*)d_in[5];
    const int*   sc_k1    = (const int*)d_in[6];
    const float* W_lin    = (const float*)d_in[7];
    const float* b_lin    = (const float*)d_in[8];
    const float* W_k0     = (const float*)d_in[9];
    const float* b_k0     = (const float*)d_in[10];
    const float* W_k1     = (const float*)d_in[11];
    const float* b_k1     = (const float*)d_in[12];
    const float* eps_k0   = (const float*)d_in[13];
    const float* eps_k1   = (const float*)d_in[14];
    float* out = (float*)d_out;

    size_t ush_elems = (size_t)DOUT_ * DIN_ + 2 * (size_t)DOUT_ * KF_ + (size_t)N_NODES * DIN_;
    size_t int_elems = 2 * (size_t)N_NODES * 2 + 2 * (size_t)N_EDGES * 2 + 512;
    size_t need = ush_elems * sizeof(unsigned short) + int_elems * sizeof(int);
    if (ws_size < need) return;  // fail loudly in validation

    unsigned short* WT_lin = (unsigned short*)d_ws;
    unsigned short* WT_k0  = WT_lin + DOUT_ * DIN_;
    unsigned short* WT_k1  = WT_k0 + DOUT_ * KF_;
    unsigned short* h_bf   = WT_k1 + DOUT_ * KF_;
    int* hist     = (int*)(h_bf + (size_t)N_NODES * DIN_);
    int* offs     = hist + 2 * N_NODES;
    int* order    = offs + 2 * N_NODES;     // [2*E]
    int* keys     = order + 2 * N_EDGES;    // [2*E]
    int* partials = keys + 2 * N_EDGES;     // [512]

    hipMemsetAsync(hist, 0, 2 * N_NODES * sizeof(int), stream);
    hist_kernel<<<(N_EDGES + 255) / 256, 256, 0, stream>>>(sc_k0, sc_k1, hist);
    scan_pass1<<<SCAN_NB, 256, 0, stream>>>(hist, partials);
    scan_pass2<<<1, 512, 0, stream>>>(partials);
    scan_pass3<<<SCAN_NB, 256, 0, stream>>>(hist, partials, offs);
    rank_kernel<<<(N_EDGES + 255) / 256, 256, 0, stream>>>(sc_k0, sc_k1, offs, order, keys);

    prep_weights<<<(DOUT_ * KF_ + 255) / 256, 256, 0, stream>>>(W_lin, W_k0, W_k1,
                                                                WT_lin, WT_k0, WT_k1);
    conv_h<<<(N_NODES * DIN_ / 8) / 256, 256, 0, stream>>>(h, h_bf);
    main_gemm<<<(N_NODES + 63) / 64, 256, 0, stream>>>(h_bf, WT_lin, b_lin, out);
    edge_gemm<<<2 * NBLK_EDGE, 256, 0, stream>>>(h_bf, pairs_k0, pairs_k1, deg_k0, deg_k1,
                                                 order, keys, WT_k0, WT_k1, b_k0, b_k1,
                                                 eps_k0, eps_k1, out);
}